// Round 3
// baseline (1346.651 us; speedup 1.0000x reference)
//
#include <hip/hip_runtime.h>

// Problem constants (B=32, d=512, T=2048)
#define BB     32
#define DD     512
#define FOURD  2048
#define TT     2048
#define TVROW  (TT / 4)    // 512 float4 per row
#define FSPLIT 10          // 8 G-splits + 2 m-splits, 256 f-rows each
#define ROWS   256
#define NBLK_PER_B (8 * FSPLIT)            // 80 blocks per batch element
#define PART_BYTES ((size_t)BB * 2 * FSPLIT * TT * 4)   // 5.24 MB partials

// ---------------------------------------------------------------------------
// Single fused kernel.
// Grid (8 tc, 10 ys, 32 b) = 2560 blocks; block = 256 threads = 4 waves.
// Wave fp reads 64 f-rows, lanes = 64 consecutive float4 (1 KB coalesced).
// ys 0..7 read G (feeds BOTH p1/p2 accumulators -> G read once);
// ys 8..9 read halves of m1 (p1) and m2 (p2).
// Partials -> ws. Last block per b (atomic counter) does both softmaxes.
// ---------------------------------------------------------------------------
__global__ __launch_bounds__(256, 4) void fused_kernel(
    const float* __restrict__ G,
    const float* __restrict__ m1,
    const float* __restrict__ m2,
    const float* __restrict__ wp1,
    const float* __restrict__ wp2,
    float* __restrict__ ws,
    unsigned int* __restrict__ counters,
    float* __restrict__ out)
{
    __shared__ float s_w1[ROWS];
    __shared__ float s_w2[ROWS];
    __shared__ float4 red1[4][64];
    __shared__ float4 red2[4][64];
    __shared__ int s_last;
    __shared__ float s_red[4];
    __shared__ float s_red2[4];

    const int tid   = threadIdx.x;
    const int tc    = blockIdx.x;   // 0..7  (256 t's each)
    const int ys    = blockIdx.y;   // 0..9  (f-split)
    const int b     = blockIdx.z;
    const int fbase = ys * ROWS;

    if (tid < ROWS) {
        s_w1[tid] = wp1[fbase + tid];
        s_w2[tid] = wp2[fbase + tid];
    }
    __syncthreads();

    const int tg = tid & 63;
    const int fp = tid >> 6;
    const int tv = tc * 64 + tg;

    float4 acc1 = make_float4(0.f, 0.f, 0.f, 0.f);
    float4 acc2 = make_float4(0.f, 0.f, 0.f, 0.f);

    if (ys < 8) {
        const float4* Gp = (const float4*)(G + (size_t)b * FOURD * TT)
                         + (size_t)(fbase + fp * 64) * TVROW + tv;
        #pragma unroll 8
        for (int i = 0; i < 64; ++i) {
            const float4 g = Gp[(size_t)i * TVROW];
            const float w1 = s_w1[fp * 64 + i];   // wave-uniform -> LDS broadcast
            const float w2 = s_w2[fp * 64 + i];
            acc1.x += w1 * g.x; acc1.y += w1 * g.y; acc1.z += w1 * g.z; acc1.w += w1 * g.w;
            acc2.x += w2 * g.x; acc2.y += w2 * g.y; acc2.z += w2 * g.z; acc2.w += w2 * g.w;
        }
    } else {
        const int r0 = (fbase - FOURD) + fp * 64;
        const float4* m1p = (const float4*)(m1 + (size_t)b * DD * TT) + (size_t)r0 * TVROW + tv;
        const float4* m2p = (const float4*)(m2 + (size_t)b * DD * TT) + (size_t)r0 * TVROW + tv;
        #pragma unroll 4
        for (int i = 0; i < 64; ++i) {
            const float4 a = m1p[(size_t)i * TVROW];
            const float4 c = m2p[(size_t)i * TVROW];
            const float w1 = s_w1[fp * 64 + i];
            const float w2 = s_w2[fp * 64 + i];
            acc1.x += w1 * a.x; acc1.y += w1 * a.y; acc1.z += w1 * a.z; acc1.w += w1 * a.w;
            acc2.x += w2 * c.x; acc2.y += w2 * c.y; acc2.z += w2 * c.z; acc2.w += w2 * c.w;
        }
    }

    red1[fp][tg] = acc1;
    red2[fp][tg] = acc2;
    __syncthreads();

    // Cross-wave reduce + partial store: threads 0..63 -> p1, 64..127 -> p2.
    if (tid < 128) {
        const int which = tid >> 6;
        const int g     = tid & 63;
        float4 s = make_float4(0.f, 0.f, 0.f, 0.f);
        #pragma unroll
        for (int p = 0; p < 4; ++p) {
            const float4 v = which ? red2[p][g] : red1[p][g];
            s.x += v.x; s.y += v.y; s.z += v.z; s.w += v.w;
        }
        float4* o = (float4*)ws
                  + ((size_t)b * 2 * FSPLIT + (size_t)which * FSPLIT + ys) * TVROW
                  + tc * 64 + g;
        *o = s;
    }

    // ---- completion protocol: last block of this b does the softmax ----
    __threadfence();              // release: cross-XCD L2 writeback
    __syncthreads();
    if (tid == 0) {
        const unsigned int old = atomicAdd(&counters[b], 1u);
        s_last = (old == NBLK_PER_B - 1);
    }
    __syncthreads();
    if (!s_last) return;
    __threadfence();              // acquire: invalidate stale L1/L2 lines

    // ---- epilogue: dual softmax for batch b ----
    // threads 0..127 -> which=0, 128..255 -> which=1; 4 float4 (16 t) each.
    const int which = tid >> 7;
    const int t2    = tid & 127;
    const float4* basev = (const float4*)ws + ((size_t)b * 2 + which) * FSPLIT * TVROW;

    float4 v4[4];
    float mx = -INFINITY;
    #pragma unroll
    for (int j = 0; j < 4; ++j) {
        const int idx = t2 + j * 128;
        float4 s = make_float4(0.f, 0.f, 0.f, 0.f);
        #pragma unroll
        for (int p = 0; p < FSPLIT; ++p) {
            const float4 t = basev[(size_t)p * TVROW + idx];
            s.x += t.x; s.y += t.y; s.z += t.z; s.w += t.w;
        }
        v4[j] = s;
        mx = fmaxf(mx, fmaxf(fmaxf(s.x, s.y), fmaxf(s.z, s.w)));
    }

    #pragma unroll
    for (int off = 32; off > 0; off >>= 1)
        mx = fmaxf(mx, __shfl_xor(mx, off, 64));
    if ((tid & 63) == 0) s_red[tid >> 6] = mx;
    __syncthreads();
    mx = fmaxf(s_red[which * 2], s_red[which * 2 + 1]);

    float sum = 0.f;
    #pragma unroll
    for (int j = 0; j < 4; ++j) {
        v4[j].x = __expf(v4[j].x - mx);
        v4[j].y = __expf(v4[j].y - mx);
        v4[j].z = __expf(v4[j].z - mx);
        v4[j].w = __expf(v4[j].w - mx);
        sum += v4[j].x + v4[j].y + v4[j].z + v4[j].w;
    }
    #pragma unroll
    for (int off = 32; off > 0; off >>= 1)
        sum += __shfl_xor(sum, off, 64);
    if ((tid & 63) == 0) s_red2[tid >> 6] = sum;
    __syncthreads();
    const float inv = 1.0f / (s_red2[which * 2] + s_red2[which * 2 + 1]);

    float4* op = (float4*)(out + ((size_t)b * 2 + which) * TT);
    #pragma unroll
    for (int j = 0; j < 4; ++j) {
        float4 r = v4[j];
        r.x *= inv; r.y *= inv; r.z *= inv; r.w *= inv;
        op[t2 + j * 128] = r;
    }
}

extern "C" void kernel_launch(void* const* d_in, const int* in_sizes, int n_in,
                              void* d_out, int out_size, void* d_ws, size_t ws_size,
                              hipStream_t stream) {
    const float* G   = (const float*)d_in[0];
    const float* m1  = (const float*)d_in[1];
    const float* m2  = (const float*)d_in[2];
    const float* wp1 = (const float*)d_in[3];
    const float* wp2 = (const float*)d_in[4];
    float* out = (float*)d_out;
    float* ws  = (float*)d_ws;
    unsigned int* counters = (unsigned int*)((char*)d_ws + PART_BYTES);

    // ws is poisoned 0xAA before every call — zero the counters (capturable).
    hipMemsetAsync(counters, 0, BB * sizeof(unsigned int), stream);

    dim3 grid(TT / 256, FSPLIT, BB);
    fused_kernel<<<grid, 256, 0, stream>>>(G, m1, m2, wp1, wp2, ws, counters, out);
}